// Round 15
// baseline (121.130 us; speedup 1.0000x reference)
//
#include <hip/hip_runtime.h>
#include <hip/hip_cooperative_groups.h>
#include <math.h>

namespace cg = cooperative_groups;

#define HH 32
#define WW 32
#define CIN 64
#define NO 64
#define NCK 576                 // CIN*9
#define X_ELEMS 262144
#define STRIDE_E 292            // LDS worklist entries per pixel-half (288+pad)

// ws float-offsets
#define WS_W    0               // Wz[ck][o] = -SZ*theta[o][ck]  (36864, coalesced in o)
#define WS_TAU  36864           // tau[ck] = SZ*min_o theta - 8, +64 pad(1e30)

__device__ __forceinline__ float fexp2(float x) {
#if __has_builtin(__builtin_amdgcn_exp2f)
    return __builtin_amdgcn_exp2f(x);
#else
    return exp2f(x);
#endif
}
__device__ __forceinline__ float flog2(float x) {
#if __has_builtin(__builtin_amdgcn_logf)
    return __builtin_amdgcn_logf(x);
#else
    return log2f(x);
#endif
}

// Single cooperative kernel: 512 blocks x 512 thr (2 blocks/CU -- comfortable
// co-residency). Prep phase (blocks 0..144, R14's prep) -> grid.sync() ->
// 2 sequential passes of R14's phase A (ballot+mbcnt LDS worklist) and
// phase B (fixed-trip quad eval, pipelined W-row loads).
__global__ __launch_bounds__(512) void ekv_kernel(
        const float* __restrict__ x, const float* __restrict__ theta,
        float* __restrict__ ws, float* __restrict__ out) {
    constexpr float SZ = 19.235933878519512f;    // log2(e)/0.075
    constexpr float C2 = 1.2726342e-3f;          // 2^(-D2), D2 = 0.5/(0.075*ln2)
    constexpr float OS = 0.020018875579925058f;  // ln2^2 * 2e-6 * 500000/24

    __shared__ int   lcm[8][STRIDE_E];           // ck worklists (per wave)
    __shared__ float lxm[8][STRIDE_E];           // xs worklists
    __shared__ float part[4][64];

    const int t    = threadIdx.x;
    const int b    = (int)blockIdx.x;
    const int lane = t & 63;
    const int wv   = __builtin_amdgcn_readfirstlane(t >> 6);  // 0..7

    // ---- prep phase (spread over blocks 0..144; waves 4..7 of each idle) ----
    if (b < 144) {
        if (t < 256) {                           // W transform + in-wave tau min
            int i = b * 256 + t;                 // i = ck*64 + o; lanes are o
            int o = i & 63, ck = i >> 6;
            float th = theta[o * NCK + ck];
            ws[WS_W + i] = -SZ * th;
            float mn = th;                       // wave-min over the 64 o's
#pragma unroll
            for (int s = 32; s > 0; s >>= 1)
                mn = fminf(mn, __shfl_xor(mn, s, 64));
            if (o == 0) ws[WS_TAU + ck] = SZ * mn - 8.0f;  // active iff z >= -8
        }
    } else if (b == 144) {
        if (t < 64) ws[WS_TAU + NCK + t] = 1e30f;          // tau pad
    }

    cg::this_grid().sync();

    const float* wsW = ws + WS_W;

    for (int pass = 0; pass < 2; ++pass) {
        const int p2  = (b * 2 + pass) * 8 + wv;  // pixel-half id (0..8191)
        const int pix = p2 >> 1, half = p2 & 1;
        const int px  = wv >> 1;                  // pixel slot within block
        const int n  = pix >> 10;
        const int ho = (pix >> 5) & 31;
        const int wo = pix & 31;
        const int c0 = half * 32;

        // ---- Phase A: build this wave's worklist in LDS ----
        int l = lane;
        int c_off = l / 9; if (c_off > 6) c_off = 6;
        int k = l - 9 * c_off; if (k > 8) k = 8;
        int di = k / 3, dj = k - 3 * (k / 3);
        int h = ho + di - 1, w_ = wo + dj - 1;
        bool sval = (h >= 0) && (h < HH) && (w_ >= 0) && (w_ < WW);
        int hc = min(max(h, 0), HH - 1), wc = min(max(w_, 0), WW - 1);
        // pad taps: xs = 0 == exact x=0 contribution if ever active
        float msc = ((l < 63) && sval) ? SZ : 0.0f;

        int gidx = n * (CIN * HH * WW) + (c0 + c_off) * 1024 + hc * WW + wc;
        const float* tw = ws + WS_TAU + c0 * 9;

        int cnt = 0;
        float xv = x[min(gidx, X_ELEMS - 1)];    // chunk 0 (OOB lanes masked)
        float tv = tw[l];

        for (int cb = 0; cb < 32; cb += 7) {
            int cc = 32 - cb; if (cc > 7) cc = 7;
            int gidx2 = gidx + 7 * 1024;
            const float* tw2 = tw + 63;
            float xvn = xv, tvn = tv;
            if (cb + 7 < 32) { xvn = x[min(gidx2, X_ELEMS - 1)]; tvn = tw2[l]; }

            float xs = xv * msc;                 // SZ*x (pad lanes: 0)
            bool a = (xs >= tv) && (l < cc * 9);
            unsigned long long act = __ballot(a);
            unsigned lo32 = (unsigned)act, hi32 = (unsigned)(act >> 32);
            int idx = __builtin_amdgcn_mbcnt_hi(hi32,
                          __builtin_amdgcn_mbcnt_lo(lo32, 0));
            if (a) {
                lcm[wv][cnt + idx] = (c0 + cb) * 9 + l;   // ck
                lxm[wv][cnt + idx] = xs;                  // SZ*x
            }
            cnt += (int)__popcll(act);           // uniform across lanes
            gidx = gidx2; tw = tw2; xv = xvn; tv = tvn;
        }
        // pad to a multiple of 4 with exact-zero dummies (z=-1e5 -> exp2 -> 0)
        int padn = (-cnt) & 3;
        if (lane < padn) { lcm[wv][cnt + lane] = 0; lxm[wv][cnt + lane] = -100000.0f; }
        const int rounds = (cnt + padn) >> 2;    // uniform

        // ---- Phase B: fixed-trip quad evaluation over this wave's list ----
        const int4*   LC = (const int4*)&lcm[wv][0];   // rows 16B-aligned
        const float4* LX = (const float4*)&lxm[wv][0];

        float accF = 0.f, accR = 0.f;

#define EKV_BODY(SX, WV)                                                   \
        {                                                                  \
            float z  = (WV) + (SX);      /* SZ*(x - theta) */              \
            float e  = fexp2(z);                                           \
            float f  = flog2(1.0f + e);                                    \
            float rr = flog2(fmaf(C2, e, 1.0f));                           \
            accF = fmaf(f, f, accF);                                       \
            accR = fmaf(rr, rr, accR);                                     \
        }

        if (rounds > 0) {
            int4   cq = LC[0];
            float4 xq = LX[0];
            for (int r = 0; r < rounds; ++r) {
                int4 cqn = cq; float4 xqn = xq;
                if (r + 1 < rounds) { cqn = LC[r + 1]; xqn = LX[r + 1]; }
                // 4 coalesced W-row loads issued before any body
                float W0 = wsW[(cq.x << 6) + lane];
                float W1 = wsW[(cq.y << 6) + lane];
                float W2 = wsW[(cq.z << 6) + lane];
                float W3 = wsW[(cq.w << 6) + lane];
                EKV_BODY(xq.x, W0)
                EKV_BODY(xq.y, W1)
                EKV_BODY(xq.z, W2)
                EKV_BODY(xq.w, W3)
                cq = cqn; xq = xqn;
            }
        }
#undef EKV_BODY

        float p = accF - accR;
        if (half == 1) part[px][lane] = p;
        __syncthreads();
        if (half == 0)
            out[((n * NO + lane) * HH + ho) * WW + wo] = (p + part[px][lane]) * OS;
        __syncthreads();                         // part[] reused next pass
    }
}

extern "C" void kernel_launch(void* const* d_in, const int* in_sizes, int n_in,
                              void* d_out, int out_size, void* d_ws, size_t ws_size,
                              hipStream_t stream) {
    const float* x     = (const float*)d_in[0];   // (4,64,32,32) fp32
    const float* theta = (const float*)d_in[1];   // (64,64,3,3) fp32
    float* out = (float*)d_out;                   // (4,64,32,32) fp32
    float* ws  = (float*)d_ws;

    void* args[] = {(void*)&x, (void*)&theta, (void*)&ws, (void*)&out};
    hipLaunchCooperativeKernel((const void*)ekv_kernel,
                               dim3(512), dim3(512), args, 0, stream);
}

// Round 16
// 74.404 us; speedup vs baseline: 1.6280x; 1.6280x over previous
//
#include <hip/hip_runtime.h>
#include <math.h>

#define HH 32
#define WW 32
#define CIN 64
#define NO 64
#define NCK 576                 // CIN*9
#define X_ELEMS 262144
#define STRIDE_E 292            // LDS worklist entries per pixel-half (288+pad)

// ws float-offsets
#define WS_W    0               // Wz[ck][o] = -SZ*theta[o][ck]  (36864, coalesced in o)
#define WS_TAU  36864           // tau[ck] = SZ*min_o theta - 8, +64 pad(1e30)

__device__ __forceinline__ float fexp2(float x) {
#if __has_builtin(__builtin_amdgcn_exp2f)
    return __builtin_amdgcn_exp2f(x);
#else
    return exp2f(x);
#endif
}
__device__ __forceinline__ float flog2(float x) {
#if __has_builtin(__builtin_amdgcn_logf)
    return __builtin_amdgcn_logf(x);
#else
    return log2f(x);
#endif
}

__global__ __launch_bounds__(256) void prep_kernel(const float* __restrict__ theta,
                                                   float* __restrict__ ws) {
    constexpr float SZ = 19.235933878519512f;    // log2(e)/0.075
    const int b = blockIdx.x, t = threadIdx.x;
    if (b < 144) {                               // W transform + in-wave tau min
        int i = b * 256 + t;                     // i = ck*64 + o; lanes are o
        int o = i & 63, ck = i >> 6;
        float th = theta[o * NCK + ck];
        ws[WS_W + i] = -SZ * th;
        float mn = th;                           // wave-min over the 64 o's
#pragma unroll
        for (int s = 32; s > 0; s >>= 1)
            mn = fminf(mn, __shfl_xor(mn, s, 64));
        if (o == 0) ws[WS_TAU + ck] = SZ * mn - 8.0f;   // active iff z >= -8
    } else {                                     // tau pad: never active
        if (t < 64) ws[WS_TAU + NCK + t] = 1e30f;
    }
}

// Block = 512 thr = 8 waves = 4 pixels x 2 c-halves.
// Phase A: all 10 gathers (5 x + 5 tau) issued up-front (independent), then
// 5 ballot+mbcnt compactions into this wave's LDS worklist.
// Phase B: fixed-trip quad loop; W-row loads rotated ONE ROUND AHEAD (8
// outstanding) to hide L3 latency under the exp2/log2 bodies.
__global__ __launch_bounds__(512) void ekv_kernel(
        const float* __restrict__ x, const float* __restrict__ ws,
        float* __restrict__ out) {
    constexpr float SZ = 19.235933878519512f;    // log2(e)/0.075
    constexpr float C2 = 1.2726342e-3f;          // 2^(-D2), D2 = 0.5/(0.075*ln2)
    constexpr float OS = 0.020018875579925058f;  // ln2^2 * 2e-6 * 500000/24

    __shared__ int   lcm[8][STRIDE_E];           // ck worklists (per wave)
    __shared__ float lxm[8][STRIDE_E];           // xs worklists
    __shared__ float part[4][64];

    const int t    = threadIdx.x;
    const int lane = t & 63;
    const int wv   = __builtin_amdgcn_readfirstlane(t >> 6);  // 0..7
    const int p2   = (int)blockIdx.x * 8 + wv;   // pixel-half id
    const int pix  = p2 >> 1, half = p2 & 1;
    const int px   = wv >> 1;                    // pixel slot within block
    const int n  = pix >> 10;
    const int ho = (pix >> 5) & 31;
    const int wo = pix & 31;
    const int c0 = half * 32;

    // ---- Phase A: build this wave's worklist in LDS ----
    int l = lane;
    int c_off = l / 9; if (c_off > 6) c_off = 6;
    int k = l - 9 * c_off; if (k > 8) k = 8;
    int di = k / 3, dj = k - 3 * (k / 3);
    int h = ho + di - 1, w_ = wo + dj - 1;
    bool sval = (h >= 0) && (h < HH) && (w_ >= 0) && (w_ < WW);
    int hc = min(max(h, 0), HH - 1), wc = min(max(w_, 0), WW - 1);
    // pad taps: xs = 0 == exact x=0 contribution if ever active; else skipped
    float msc = ((l < 63) && sval) ? SZ : 0.0f;

    const int gidx0 = n * (CIN * HH * WW) + (c0 + c_off) * 1024 + hc * WW + wc;
    const float* tw = ws + WS_TAU + c0 * 9;

    // all 10 independent gathers issued before any use (one vmcnt ladder)
    float xv[5], tv[5];
#pragma unroll
    for (int i = 0; i < 5; ++i) {
        int g = gidx0 + i * 7 * 1024;
        xv[i] = x[min(g, X_ELEMS - 1)];          // OOB lanes masked below
        tv[i] = tw[l + i * 63];                  // tau region padded to 640
    }

    int cnt = 0;
#pragma unroll
    for (int i = 0; i < 5; ++i) {
        const int cb = i * 7;
        const int cc = (32 - cb) < 7 ? (32 - cb) : 7;
        float xs = xv[i] * msc;                  // SZ*x (pad lanes: 0)
        bool a = (xs >= tv[i]) && (l < cc * 9);
        unsigned long long act = __ballot(a);
        unsigned lo32 = (unsigned)act, hi32 = (unsigned)(act >> 32);
        int idx = __builtin_amdgcn_mbcnt_hi(hi32,
                      __builtin_amdgcn_mbcnt_lo(lo32, 0));
        if (a) {
            lcm[wv][cnt + idx] = (c0 + cb) * 9 + l;   // ck
            lxm[wv][cnt + idx] = xs;                  // SZ*x
        }
        cnt += (int)__popcll(act);               // uniform across lanes
    }
    // pad to a multiple of 4 with exact-zero dummies (z=-1e5 -> exp2 -> 0)
    int padn = (-cnt) & 3;
    if (lane < padn) { lcm[wv][cnt + lane] = 0; lxm[wv][cnt + lane] = -100000.0f; }
    const int rounds = (cnt + padn) >> 2;        // uniform

    // ---- Phase B: quad evaluation, W-loads rotated one round ahead ----
    const int4*   LC = (const int4*)&lcm[wv][0]; // rows are 16B-aligned
    const float4* LX = (const float4*)&lxm[wv][0];
    const float* wsW = ws + WS_W;

    float accF = 0.f, accR = 0.f;

#define EKV_BODY(SX, WV)                                                   \
    {                                                                      \
        float z  = (WV) + (SX);      /* SZ*(x - theta) */                  \
        float e  = fexp2(z);                                               \
        float f  = flog2(1.0f + e);                                        \
        float rr = flog2(fmaf(C2, e, 1.0f));                               \
        accF = fmaf(f, f, accF);                                           \
        accR = fmaf(rr, rr, accR);                                         \
    }

    if (rounds > 0) {
        int4   cq = LC[0];
        float4 xq = LX[0];
        float W0 = wsW[(cq.x << 6) + lane];
        float W1 = wsW[(cq.y << 6) + lane];
        float W2 = wsW[(cq.z << 6) + lane];
        float W3 = wsW[(cq.w << 6) + lane];
        for (int r = 0; r < rounds; ++r) {
            int4   cqn = cq;
            float4 xqn = xq;
            float V0 = W0, V1 = W1, V2 = W2, V3 = W3;
            if (r + 1 < rounds) {
                cqn = LC[r + 1];                 // LDS (fast) -> issue next
                xqn = LX[r + 1];                 // round's W-loads before
                V0 = wsW[(cqn.x << 6) + lane];   // this round's bodies
                V1 = wsW[(cqn.y << 6) + lane];
                V2 = wsW[(cqn.z << 6) + lane];
                V3 = wsW[(cqn.w << 6) + lane];
            }
            EKV_BODY(xq.x, W0)
            EKV_BODY(xq.y, W1)
            EKV_BODY(xq.z, W2)
            EKV_BODY(xq.w, W3)
            cq = cqn; xq = xqn;
            W0 = V0; W1 = V1; W2 = V2; W3 = V3;
        }
    }
#undef EKV_BODY

    float p = accF - accR;
    if (half == 1) part[px][lane] = p;
    __syncthreads();
    if (half == 0)
        out[((n * NO + lane) * HH + ho) * WW + wo] = (p + part[px][lane]) * OS;
}

extern "C" void kernel_launch(void* const* d_in, const int* in_sizes, int n_in,
                              void* d_out, int out_size, void* d_ws, size_t ws_size,
                              hipStream_t stream) {
    const float* x     = (const float*)d_in[0];   // (4,64,32,32) fp32
    const float* theta = (const float*)d_in[1];   // (64,64,3,3) fp32
    float* out = (float*)d_out;                   // (4,64,32,32) fp32
    float* ws  = (float*)d_ws;

    prep_kernel<<<145, 256, 0, stream>>>(theta, ws);
    ekv_kernel <<<1024, 512, 0, stream>>>(x, ws, out);  // build+eval fused
}